// Round 1
// baseline (376.505 us; speedup 1.0000x reference)
//
#include <hip/hip_runtime.h>

// CRF loss (NERTagger). BS=1024 sequences, SL=512 steps, NC=50 classes.
// Decomposition:
//   scan kernel : wave-per-b (1024 waves = 256 blocks x 4 waves), lane-per-class.
//                 Per step: new_a[j] = x[j] + log(sum_i exp(a[i]) * eT[i][j]),
//                 with running shift C (renormalize by lane-0 value, readfirstlane).
//                 unary/binary fused. Break at first masked t (masks monotone).
//   finish      : reduce 1024 per-b log-likelihoods -> loss at d_out[0].
//   copy        : transitions passthrough -> d_out[1..2500].

#define BS 1024
#define SL 512
#define NC 50

__launch_bounds__(256)
__global__ void crf_scan(const float* __restrict__ inputs,
                         const float* __restrict__ trans,
                         const int* __restrict__ masks,
                         const int* __restrict__ tags,
                         float* __restrict__ ll_out) {
  __shared__ float T_s[NC * NC];
  __shared__ float ea_s[4][64];

  const int tid = threadIdx.x;
  for (int k = tid; k < NC * NC; k += 256) T_s[k] = trans[k];
  __syncthreads();

  const int w = tid >> 6;                 // wave in block
  const int j = tid & 63;                 // lane = class index
  const int b = blockIdx.x * 4 + w;       // 256 blocks * 4 = 1024
  const bool jv = (j < NC);
  const int jj = jv ? j : (NC - 1);       // clamped for safe loads

  // eT column j in registers (static indices only -> stays in VGPRs)
  float eTcol[NC];
#pragma unroll
  for (int i = 0; i < NC; ++i) eTcol[i] = __expf(T_s[i * NC + jj]);

  const float* __restrict__ xrow = inputs + (size_t)b * SL * NC;
  const int* __restrict__ mrow = masks + b * SL;
  const int* __restrict__ grow = tags + b * SL;

  // t = 0 (mask[b][0] is always false: lengths >= SL/4)
  float a = xrow[jj];                     // alpha_rel, lane j
  int tag = grow[0];
  float un = (j == tag) ? a : 0.0f;       // unary accumulator (per-lane)
  if (!jv) a = -1e30f;
  float bi = 0.0f;                        // binary accumulator (wave-uniform)
  float C = 0.0f;                         // running shift: alpha = a + C
  int tprev = tag;

  // 2-deep prefetch (named regs, no runtime-indexed arrays)
  float xA = xrow[1 * NC + jj];
  float xB = xrow[2 * NC + jj];
  int mA = mrow[1], mB = mrow[2];
  int gA = grow[1], gB = grow[2];

  auto STEP = [&](float x, int tg) {
    un += (j == tg) ? x : 0.0f;
    bi += T_s[tprev * NC + tg];           // uniform LDS broadcast read
    tprev = tg;

    float ea = __expf(a);                 // lanes >= NC: exp(-1e30) = 0
    ea_s[w][j] = ea;
    __asm__ volatile("s_waitcnt lgkmcnt(0)" ::: "memory");

    float s0 = 0.f, s1 = 0.f, s2 = 0.f, s3 = 0.f;
#pragma unroll
    for (int i = 0; i < 12; ++i) {        // 48 of 50, b128 broadcast reads
      const float4 e = *reinterpret_cast<const float4*>(&ea_s[w][i * 4]);
      s0 = fmaf(e.x, eTcol[i * 4 + 0], s0);
      s1 = fmaf(e.y, eTcol[i * 4 + 1], s1);
      s2 = fmaf(e.z, eTcol[i * 4 + 2], s2);
      s3 = fmaf(e.w, eTcol[i * 4 + 3], s3);
    }
    {
      const float2 e = *reinterpret_cast<const float2*>(&ea_s[w][48]);
      s0 = fmaf(e.x, eTcol[48], s0);
      s1 = fmaf(e.y, eTcol[49], s1);
    }
    const float s = (s0 + s1) + (s2 + s3);            // > 0 always (a[0]=0 -> ea[0]=1)
    const float anew = x + __logf(s);                 // alpha_new - C
    const float shift =
        __int_as_float(__builtin_amdgcn_readfirstlane(__float_as_int(anew)));
    C += shift;
    a = jv ? (anew - shift) : -1e30f;                 // lane0 -> exactly 0
  };

  for (int t = 1; t < SL; t += 2) {
    if (mA) goto done;                    // masks monotone: done with this b
    {
      const float x = xA; const int tg = gA;
      int tn = t + 2; tn = (tn < SL) ? tn : (SL - 1);
      xA = xrow[tn * NC + jj]; mA = mrow[tn]; gA = grow[tn];
      STEP(x, tg);
    }
    if (t + 1 >= SL) break;               // t = 511 handled above
    if (mB) goto done;
    {
      const float x = xB; const int tg = gB;
      int tn = t + 3; tn = (tn < SL) ? tn : (SL - 1);
      xB = xrow[tn * NC + jj]; mB = mrow[tn]; gB = grow[tn];
      STEP(x, tg);
    }
  }
done:
  // log_norm = C + log(sum_j exp(a_j)); ll = unary + binary - log_norm
  float ev = jv ? __expf(a) : 0.0f;
  float us = un;
#pragma unroll
  for (int m = 32; m >= 1; m >>= 1) {
    ev += __shfl_xor(ev, m, 64);
    us += __shfl_xor(us, m, 64);
  }
  if (j == 0) ll_out[b] = us + bi - (C + __logf(ev));
}

__global__ void crf_finish(const float* __restrict__ ll, float* __restrict__ out) {
  __shared__ float red[256];
  const int tid = threadIdx.x;
  float v = 0.f;
  for (int k = tid; k < BS; k += 256) v += ll[k];
  red[tid] = v;
  __syncthreads();
  if (tid < 64) {
    v = red[tid] + red[tid + 64] + red[tid + 128] + red[tid + 192];
#pragma unroll
    for (int m = 32; m >= 1; m >>= 1) v += __shfl_xor(v, m, 64);
    if (tid == 0) out[0] = -v / (float)BS;
  }
}

__global__ void copy_trans(const float* __restrict__ trans, float* __restrict__ out) {
  const int k = blockIdx.x * 256 + threadIdx.x;
  if (k < NC * NC) out[1 + k] = trans[k];
}

extern "C" void kernel_launch(void* const* d_in, const int* in_sizes, int n_in,
                              void* d_out, int out_size, void* d_ws, size_t ws_size,
                              hipStream_t stream) {
  const float* inputs = (const float*)d_in[0];
  const float* trans  = (const float*)d_in[1];
  const int*   masks  = (const int*)d_in[2];   // jnp bool -> harness int32 convention
  const int*   tags   = (const int*)d_in[3];
  float* out = (float*)d_out;                  // [0]=loss, [1..2500]=transitions
  float* ll  = (float*)d_ws;                   // 1024 per-b log-likelihoods

  crf_scan<<<256, 256, 0, stream>>>(inputs, trans, masks, tags, ll);
  crf_finish<<<1, 256, 0, stream>>>(ll, out);
  copy_trans<<<(NC * NC + 255) / 256, 256, 0, stream>>>(trans, out);
}

// Round 2
// 277.859 us; speedup vs baseline: 1.3550x; 1.3550x over previous
//
#include <hip/hip_runtime.h>

// CRF loss, bidirectional exp-domain scan.
// Block = 1 sequence, 128 threads = 2 waves: w0 = forward alpha scan (t=1..mid),
// w1 = backward beta scan (t=L-1..mid+1) + unary/binary gather. Combine:
// logZ = Cf + Cb + log(sum_j Af_j * Bb_j);  ll = (unary+binary) - logZ.
// Exp domain: A_j = exp(alpha_j - C), renormalized every step by lane-0 value
// (readfirstlane + v_rcp, ~16 cyc on-chain); C += log(r) accumulates OFF the
// dependency chain. x rows prefetched 4 deep (>= HBM latency at ~300cyc/step).

#define BS 1024
#define SL 512
#define NC 50

__global__ void pre_kernel(const float* __restrict__ trans, float* __restrict__ out) {
  const int k = blockIdx.x * 256 + threadIdx.x;
  if (k == 0) out[0] = 0.0f;
  if (k < NC * NC) out[1 + k] = trans[k];
}

__launch_bounds__(128)
__global__ void crf_scan(const float* __restrict__ inputs,
                         const float* __restrict__ trans,
                         const int* __restrict__ masks,
                         const int* __restrict__ tags,
                         float* __restrict__ out) {
  __shared__ float T_s[NC * NC];
  __shared__ __align__(16) float bc[2][64];   // per-wave broadcast buffer
  __shared__ float Bb_s[64];                   // beta_mid (exp domain) from w1
  __shared__ float scal[2];                    // [0]=Cb, [1]=unary+binary

  const int tid = threadIdx.x;
  const int w = tid >> 6;
  const int j = tid & 63;
  const int b = blockIdx.x;
  const bool jv = (j < NC);
  const int jj = jv ? j : (NC - 1);

  for (int k = tid; k < NC * NC; k += 128) T_s[k] = trans[k];
  __syncthreads();

  const float* __restrict__ xr = inputs + (size_t)b * SL * NC;
  const int* __restrict__ mr = masks + b * SL;
  const int* __restrict__ gr = tags + b * SL;

  // ---- find L (first masked t); masks monotone, L in [128, 512] ----
  int L = SL;
  for (int c = 0; c < 8; ++c) {
    const int m = mr[c * 64 + j];
    const unsigned long long bal = __ballot(m != 0);
    if (bal) { L = c * 64 + (int)__builtin_ctzll(bal); break; }
  }
  const int mid = L >> 1;

  float A;      // w0: alpha in exp domain (normalized)
  float Cf = 0.0f;

  if (w == 0) {
    // ================== FORWARD ==================
    float eTc[NC];
#pragma unroll
    for (int i = 0; i < NC; ++i) eTc[i] = __expf(T_s[i * NC + jj]);

    A = __expf(xr[jj]);            // alpha_0 = x_0 (exp domain, C=0)

    float xc = xr[1 * NC + jj];
    float pa = xr[2 * NC + jj];
    float pb = xr[3 * NC + jj];
    float pc = xr[4 * NC + jj];

    for (int t = 1; t <= mid; ++t) {
      const float ex = __expf(xc);           // off-chain (xc loaded 4 steps ago)
      bc[0][j] = A;                          // broadcast alpha
      float s0 = 0.f, s1 = 0.f, s2 = 0.f, s3 = 0.f;
#pragma unroll
      for (int i = 0; i < 12; ++i) {
        const float4 e = *reinterpret_cast<const float4*>(&bc[0][i * 4]);
        s0 = fmaf(e.x, eTc[i * 4 + 0], s0);
        s1 = fmaf(e.y, eTc[i * 4 + 1], s1);
        s2 = fmaf(e.z, eTc[i * 4 + 2], s2);
        s3 = fmaf(e.w, eTc[i * 4 + 3], s3);
      }
      {
        const float2 e = *reinterpret_cast<const float2*>(&bc[0][48]);
        s0 = fmaf(e.x, eTc[48], s0);
        s1 = fmaf(e.y, eTc[49], s1);
      }
      const float s = (s0 + s1) + (s2 + s3);
      const float Ap = ex * s;               // alpha' (exp domain, unnormalized)
      const float r =
          __int_as_float(__builtin_amdgcn_readfirstlane(__float_as_int(Ap)));
      Cf += __logf(r);                       // OFF-chain accumulator
      A = Ap * __builtin_amdgcn_rcpf(r);     // lane0 -> exactly 1

      // rotate 4-deep prefetch
      xc = pa; pa = pb; pb = pc;
      int tn = t + 4; tn = (tn < SL) ? tn : (SL - 1);
      pc = xr[tn * NC + jj];
    }
  } else {
    // ================== BACKWARD + unary/binary ==================
    float eTr[NC];
#pragma unroll
    for (int i = 0; i < NC; ++i) eTr[i] = __expf(T_s[jj * NC + i]);

    // unary + binary gather, lane-parallel over t
    float u = 0.0f;
    for (int c = 0; c < 8; ++c) {
      const int t = c * 64 + j;
      const int tg = gr[t];
      const bool valid = (t < L);
      const float xv = xr[t * NC + tg];
      if (valid) u += xv;
      if (valid && t >= 1) u += T_s[gr[t - 1] * NC + tg];
    }
#pragma unroll
    for (int m = 32; m; m >>= 1) u += __shfl_xor(u, m, 64);

    // beta scan: t = L-1 down to mid+1
    float B = 1.0f;                          // beta_{L-1} = 0 -> exp = 1
    float Cb = 0.0f;
    float xc = xr[(L - 1) * NC + jj];
    float pa = xr[(L - 2) * NC + jj];
    float pb = xr[(L - 3) * NC + jj];
    float pc = xr[(L - 4) * NC + jj];

    for (int t = L - 1; t > mid; --t) {
      const float ex = __expf(xc);
      bc[1][j] = ex * B;                     // broadcast exp(x_t)*B
      float s0 = 0.f, s1 = 0.f, s2 = 0.f, s3 = 0.f;
#pragma unroll
      for (int i = 0; i < 12; ++i) {
        const float4 e = *reinterpret_cast<const float4*>(&bc[1][i * 4]);
        s0 = fmaf(e.x, eTr[i * 4 + 0], s0);
        s1 = fmaf(e.y, eTr[i * 4 + 1], s1);
        s2 = fmaf(e.z, eTr[i * 4 + 2], s2);
        s3 = fmaf(e.w, eTr[i * 4 + 3], s3);
      }
      {
        const float2 e = *reinterpret_cast<const float2*>(&bc[1][48]);
        s0 = fmaf(e.x, eTr[48], s0);
        s1 = fmaf(e.y, eTr[49], s1);
      }
      const float s = (s0 + s1) + (s2 + s3);
      const float r =
          __int_as_float(__builtin_amdgcn_readfirstlane(__float_as_int(s)));
      Cb += __logf(r);                       // OFF-chain
      B = s * __builtin_amdgcn_rcpf(r);

      xc = pa; pa = pb; pb = pc;
      int tn = t - 4; tn = (tn >= 0) ? tn : 0;
      pc = xr[tn * NC + jj];
    }

    Bb_s[j] = B;
    if (j == 0) { scal[0] = Cb; scal[1] = u; }
  }

  __syncthreads();

  if (w == 0) {
    // combine: logZ = Cf + Cb + log(sum_j Af_j * Bb_j)
    float prod = jv ? (A * Bb_s[j]) : 0.0f;
#pragma unroll
    for (int m = 32; m; m >>= 1) prod += __shfl_xor(prod, m, 64);
    if (j == 0) {
      const float logZ = Cf + scal[0] + __logf(prod);
      const float ll = scal[1] - logZ;
      atomicAdd(out, -ll * (1.0f / (float)BS));
    }
  }
}

extern "C" void kernel_launch(void* const* d_in, const int* in_sizes, int n_in,
                              void* d_out, int out_size, void* d_ws, size_t ws_size,
                              hipStream_t stream) {
  const float* inputs = (const float*)d_in[0];
  const float* trans  = (const float*)d_in[1];
  const int*   masks  = (const int*)d_in[2];
  const int*   tags   = (const int*)d_in[3];
  float* out = (float*)d_out;   // [0]=loss, [1..2500]=transitions

  pre_kernel<<<(NC * NC + 256) / 256, 256, 0, stream>>>(trans, out);
  crf_scan<<<BS, 128, 0, stream>>>(inputs, trans, masks, tags, out);
}